// Round 1
// baseline (331.781 us; speedup 1.0000x reference)
//
#include <hip/hip_runtime.h>
#include <hip/hip_cooperative_groups.h>
#include <hip/hip_bf16.h>
#include <math.h>

// Problem constants (from reference)
#define B_ROWS 4096
#define C_ROWS 2048
#define D_DIM  2048
#define NUM 2
#define MAX_ITER 15
#define NEAREST 3
#define MARGIN 1.0f

namespace cg = cooperative_groups;

typedef __bf16 bf16_t;
typedef bf16_t bf16x8 __attribute__((ext_vector_type(8)));
typedef float f32x4 __attribute__((ext_vector_type(4)));
typedef int i32x4 __attribute__((ext_vector_type(4)));
typedef int i32x8 __attribute__((ext_vector_type(8)));   // 32 fp8 bytes = scaled-MFMA fragment
typedef unsigned char u8;

// ---------------------------------------------------------------------------
// Phase bodies as __device__ functions — shared between the standalone
// kernels (fallback path) and the fused cooperative megakernel, so the
// verified arithmetic (absmax 0.0, R13/R14) exists exactly once.
// ---------------------------------------------------------------------------

// conv: one wave per row, f32 -> fp8 e4m3 (HW cvt_pk) + exact f32 row sumsq.
__device__ __forceinline__ void conv_row(int row,
                                         const float* __restrict__ F,
                                         const float* __restrict__ Cn,
                                         u8* __restrict__ Fq, u8* __restrict__ Cq,
                                         float* __restrict__ f2, float* __restrict__ c2,
                                         int lane) {
    const float* p; u8* q; float* sq; int r;
    if (row < B_ROWS) {
        r = row; p = F + (size_t)r * D_DIM; q = Fq + (size_t)r * D_DIM; sq = f2;
    } else {
        r = row - B_ROWS; p = Cn + (size_t)r * D_DIM; q = Cq + (size_t)r * D_DIM; sq = c2;
    }
    float s = 0.0f;
    #pragma unroll
    for (int it = 0; it < 4; ++it) {
        int k = (it * 64 + lane) * 8;         // 8 consecutive floats per lane
        float4 v0 = *(const float4*)(p + k);
        float4 v1 = *(const float4*)(p + k + 4);
        s += v0.x * v0.x + v0.y * v0.y + v0.z * v0.z + v0.w * v0.w;
        s += v1.x * v1.x + v1.y * v1.y + v1.z * v1.z + v1.w * v1.w;
        int lo = __builtin_amdgcn_cvt_pk_fp8_f32(v0.x, v0.y, 0, 0);
        lo     = __builtin_amdgcn_cvt_pk_fp8_f32(v0.z, v0.w, lo, 1);
        int hi = __builtin_amdgcn_cvt_pk_fp8_f32(v1.x, v1.y, 0, 0);
        hi     = __builtin_amdgcn_cvt_pk_fp8_f32(v1.z, v1.w, hi, 1);
        int2 st; st.x = lo; st.y = hi;
        *(int2*)(q + k) = st;                 // 8 bytes, coalesced
    }
    #pragma unroll
    for (int off = 32; off >= 1; off >>= 1) s += __shfl_down(s, off);
    if (lane == 0) sq[r] = s;
}

// Fused fp8 distance GEMM tile, MX-scaled K=128 MFMA (scale=1.0).
// Layout (R14, measured): BK=128 as two [128 rows][64 B] K-panels; XOR bank
// swizzle — 16B chunk c of row r lives at slot c ^ ((r>>1)&3); staged via
// global_load_lds (within-row lane permutation keeps 4-lane/64B coalescing).
// MEASURED PITFALLS (do not revisit): R5 128B-row banking; R7 nonzero imm
// offset on global_load_lds; R11 per-lane ROW scatter; R13 unswizzled rows.
__device__ __forceinline__ void gemm_tile(int bxn, int byy,
                                          const u8* __restrict__ Fq,
                                          const u8* __restrict__ Cq,
                                          const float* __restrict__ f2,
                                          const float* __restrict__ c2,
                                          bf16_t* __restrict__ Dfc,
                                          bf16_t* __restrict__ Dcc,
                                          u8 (*As)[128 * 64], u8 (*Bs)[128 * 64]) {
    const int tid  = threadIdx.x;
    const int wave = tid >> 6;
    const int lane = tid & 63;

    const u8* A; const float* a2v; bf16_t* Out; int bm;
    if (byy < B_ROWS / 128) { A = Fq; a2v = f2; Out = Dfc; bm = byy * 128; }
    else { A = Cq; a2v = c2; Out = Dcc; bm = (byy - B_ROWS / 128) * 128; }
    const int bn = bxn * 128;
    const int N = C_ROWS, K = D_DIM;

    const int wm = (wave >> 1) * 64;
    const int wn = (wave & 1) * 64;

    f32x4 acc[4][4] = {};

    const int c0   = wave * 2;            // staging chunks 2w, 2w+1 (16 rows)
    const int rsub = lane >> 2;           // 0..15 row within chunk
    const int kbyt = ((lane & 3) ^ ((lane >> 3) & 3)) * 16;
    const int mrow = lane & 15;
    const int swr  = (mrow >> 1) & 3;     // read-side swizzle for this lane's row
    const int kg   = lane >> 4;           // k-group 0..3
    const int pnl  = kg >> 1;             // panel this lane reads
    const int half = kg & 1;              // 32B half within the 64B row
    const int sl0  = ((half * 2    ) ^ swr) * 16;
    const int sl1  = ((half * 2 + 1) ^ swr) * 16;

    for (int k0 = 0; k0 < K; k0 += 128) {
        #pragma unroll
        for (int pn = 0; pn < 2; ++pn) {       // K-panel: k0 + pn*64 + [0,64)
            #pragma unroll
            for (int t = 0; t < 2; ++t) {
                int chunk = c0 + t;
                int row = chunk * 16 + rsub;
                const u8* gA = A  + (size_t)(bm + row) * K + (k0 + pn * 64 + kbyt);
                const u8* gB = Cq + (size_t)(bn + row) * K + (k0 + pn * 64 + kbyt);
                __builtin_amdgcn_global_load_lds(
                    (const __attribute__((address_space(1))) void*)gA,
                    (__attribute__((address_space(3))) void*)&As[pn][chunk * 1024], 16, 0, 0);
                __builtin_amdgcn_global_load_lds(
                    (const __attribute__((address_space(1))) void*)gB,
                    (__attribute__((address_space(3))) void*)&Bs[pn][chunk * 1024], 16, 0, 0);
            }
        }
        __syncthreads();

        // One K=128 step: 8 fragments x 2 ds_read_b128, 16 scaled MFMAs.
        i32x8 af[4], bf_[4];
        #pragma unroll
        for (int i = 0; i < 4; ++i) {
            int offA = (wm + i * 16 + mrow) * 64;
            int offB = (wn + i * 16 + mrow) * 64;
            i32x4 alo = *(const i32x4*)&As[pnl][offA + sl0];
            i32x4 ahi = *(const i32x4*)&As[pnl][offA + sl1];
            i32x4 blo = *(const i32x4*)&Bs[pnl][offB + sl0];
            i32x4 bhi = *(const i32x4*)&Bs[pnl][offB + sl1];
            af[i][0] = alo.x; af[i][1] = alo.y; af[i][2] = alo.z; af[i][3] = alo.w;
            af[i][4] = ahi.x; af[i][5] = ahi.y; af[i][6] = ahi.z; af[i][7] = ahi.w;
            bf_[i][0] = blo.x; bf_[i][1] = blo.y; bf_[i][2] = blo.z; bf_[i][3] = blo.w;
            bf_[i][4] = bhi.x; bf_[i][5] = bhi.y; bf_[i][6] = bhi.z; bf_[i][7] = bhi.w;
        }
        #pragma unroll
        for (int i = 0; i < 4; ++i)
            #pragma unroll
            for (int j = 0; j < 4; ++j)
                acc[i][j] = __builtin_amdgcn_mfma_scale_f32_16x16x128_f8f6f4(
                    af[i], bf_[j], acc[i][j],
                    0, 0,                 // cbsz=0 (A fp8 e4m3), blgp=0 (B fp8)
                    0, 0x7F7F7F7F,        // scale A: E8M0 1.0 in every byte
                    0, 0x7F7F7F7F);       // scale B: 1.0
        __syncthreads();
    }

    // Epilogue: d2 = a2[m] + c2[n] - 2*dot, stored bf16.
    // C/D layout shape-determined, dtype-independent: col=lane&15, row=(lane>>4)*4+reg
    const int ncol = lane & 15;
    const int r4   = (lane >> 4) * 4;
    #pragma unroll
    for (int i = 0; i < 4; ++i) {
        #pragma unroll
        for (int r = 0; r < 4; ++r) {
            int m = bm + wm + i * 16 + r4 + r;
            float am = a2v[m];
            #pragma unroll
            for (int j = 0; j < 4; ++j) {
                int n = bn + wn + j * 16 + ncol;
                Out[(size_t)m * N + n] = (bf16_t)(am + c2[n] - 2.0f * acc[i][j][r]);
            }
        }
    }
}

// select: one wave per feature row. Iterative argmin w/ exclusion over Dfc
// row; on-demand trust from Dcc via lexicographic rank count.
// Returns the hinge value (valid on lane 0 only).
__device__ __forceinline__ float select_row(int b,
                                            const bf16_t* __restrict__ Dfc,
                                            const bf16_t* __restrict__ Dcc,
                                            int lane) {
    int label = b / NUM;
    const bf16_t* row = Dfc + (size_t)b * C_ROWS;

    float vals[32];
    #pragma unroll
    for (int g = 0; g < 4; ++g) {
        bf16x8 v = *(const bf16x8*)(row + g * 512 + lane * 8);
        #pragma unroll
        for (int e = 0; e < 8; ++e) {
            int n = g * 512 + lane * 8 + e;
            float f = (float)v[e];
            vals[g * 8 + e] = (n == label) ? INFINITY : f;
        }
    }

    unsigned int excl = 0;
    float min_diff = 0.0f;
    int found = 0;
    for (int it = 0; it < MAX_ITER; ++it) {
        float bestv = INFINITY; int bestidx = 0x7fffffff;
        #pragma unroll
        for (int g = 0; g < 4; ++g)
            #pragma unroll
            for (int e = 0; e < 8; ++e) {
                int bit = g * 8 + e;
                if (excl & (1u << bit)) continue;
                float v = vals[bit];
                int idx = g * 512 + lane * 8 + e;
                if (v < bestv || (v == bestv && idx < bestidx)) { bestv = v; bestidx = idx; }
            }
        for (int off = 32; off >= 1; off >>= 1) {
            float ov = __shfl_down(bestv, off); int oi = __shfl_down(bestidx, off);
            if (ov < bestv || (ov == bestv && oi < bestidx)) { bestv = ov; bestidx = oi; }
        }
        int sel = __shfl(bestidx, 0);
        float selv = __shfl(bestv, 0);

        // on-demand trust: count lex-smaller entries of Dcc row sel
        const bf16_t* crow = Dcc + (size_t)sel * C_ROWS;
        float dl = (float)crow[label];          // uniform address: broadcast
        int cnt = 0;
        #pragma unroll
        for (int g = 0; g < 4; ++g) {
            bf16x8 v = *(const bf16x8*)(crow + g * 512 + lane * 8);
            #pragma unroll
            for (int e = 0; e < 8; ++e) {
                int idx = g * 512 + lane * 8 + e;
                float f = (float)v[e];
                cnt += (f < dl || (f == dl && idx < label)) ? 1 : 0;
            }
        }
        #pragma unroll
        for (int off = 32; off >= 1; off >>= 1) cnt += __shfl_down(cnt, off);
        cnt = __shfl(cnt, 0);
        bool trusted = (cnt >= NEAREST);

        if (trusted) { min_diff = sqrtf(fmaxf(selv, 0.0f)); found = 1; break; }
        if (((sel >> 3) & 63) == lane) excl |= 1u << (((sel >> 9) << 3) | (sel & 7));
    }
    float same = sqrtf(fmaxf((float)row[label], 0.0f));
    float md = found ? min_diff : 0.0f;
    return fmaxf(MARGIN + same - md, 0.0f);
}

// ---------------------------------------------------------------------------
// Fused cooperative megakernel: conv | grid.sync | gemm | grid.sync | select.
// Grid = 768 blocks x 256 threads = exactly the GEMM tile count AND exactly
// 3 blocks/CU x 256 CUs co-residency (guaranteed by __launch_bounds__(256,3)
// + 32KB LDS), so the cooperative launch capacity check passes with zero
// margin games. Phases 1/3 grid-stride: 3072 waves cover 6144 conv rows and
// 4096 select rows.
// ---------------------------------------------------------------------------
__global__ __launch_bounds__(256, 3) void fused_all(const float* __restrict__ F,
                                                    const float* __restrict__ Cn,
                                                    u8* __restrict__ Fq, u8* __restrict__ Cq,
                                                    float* __restrict__ f2, float* __restrict__ c2,
                                                    bf16_t* __restrict__ Dfc, bf16_t* __restrict__ Dcc,
                                                    float* __restrict__ out) {
    __shared__ __align__(16) u8 As[2][128 * 64];
    __shared__ __align__(16) u8 Bs[2][128 * 64];
    __shared__ float hs[4];

    cg::grid_group grid = cg::this_grid();
    const int wave = threadIdx.x >> 6;
    const int lane = threadIdx.x & 63;
    const int gw   = blockIdx.x * 4 + wave;       // 0..3071 global wave id

    // --- phase 1: quantize + row sumsq (2 rows per wave: gw, gw+3072) ---
    if (blockIdx.x == 0 && threadIdx.x == 0) out[0] = 0.0f;
    conv_row(gw,        F, Cn, Fq, Cq, f2, c2, lane);
    conv_row(gw + 3072, F, Cn, Fq, Cq, f2, c2, lane);
    grid.sync();

    // --- phase 2: both distance matrices; blockIdx.x IS the tile id ---
    gemm_tile(blockIdx.x & 15, blockIdx.x >> 4, Fq, Cq, f2, c2, Dfc, Dcc, As, Bs);
    grid.sync();

    // --- phase 3: select (rows gw and gw+3072 when present) ---
    float h = select_row(gw, Dfc, Dcc, lane);
    if (gw + 3072 < B_ROWS) h += select_row(gw + 3072, Dfc, Dcc, lane);
    if (lane == 0) hs[wave] = h;
    __syncthreads();
    if (threadIdx.x == 0)
        atomicAdd(out, (hs[0] + hs[1] + hs[2] + hs[3]) * (1.0f / (float)B_ROWS));
}

// ---------------------------------------------------------------------------
// Standalone kernels (fallback path if cooperative launch is unavailable
// under graph capture) — same device-function bodies.
// ---------------------------------------------------------------------------
__global__ __launch_bounds__(256) void conv_rows(const float* __restrict__ F,
                                                 const float* __restrict__ Cn,
                                                 u8* __restrict__ Fq,
                                                 u8* __restrict__ Cq,
                                                 float* __restrict__ f2,
                                                 float* __restrict__ c2,
                                                 float* __restrict__ out) {
    if (blockIdx.x == 0 && threadIdx.x == 0) out[0] = 0.0f;
    int wave = threadIdx.x >> 6;
    int lane = threadIdx.x & 63;
    int row = blockIdx.x * 4 + wave;          // 0..6143
    conv_row(row, F, Cn, Fq, Cq, f2, c2, lane);
}

__global__ __launch_bounds__(256, 3) void gemm_d2_fused(const u8* __restrict__ Fq,
                                                        const u8* __restrict__ Cq,
                                                        const float* __restrict__ f2,
                                                        const float* __restrict__ c2,
                                                        bf16_t* __restrict__ Dfc,
                                                        bf16_t* __restrict__ Dcc) {
    __shared__ __align__(16) u8 As[2][128 * 64];
    __shared__ __align__(16) u8 Bs[2][128 * 64];
    gemm_tile(blockIdx.x, blockIdx.y, Fq, Cq, f2, c2, Dfc, Dcc, As, Bs);
}

__global__ __launch_bounds__(256) void select_kernel(const bf16_t* __restrict__ Dfc,
                                                     const bf16_t* __restrict__ Dcc,
                                                     float* __restrict__ out, int C) {
    int wave = threadIdx.x >> 6, lane = threadIdx.x & 63;
    int b = blockIdx.x * 4 + wave;
    float h = select_row(b, Dfc, Dcc, lane);
    __shared__ float hs[4];
    if (lane == 0) hs[wave] = h;
    __syncthreads();
    if (threadIdx.x == 0)
        atomicAdd(out, (hs[0] + hs[1] + hs[2] + hs[3]) * (1.0f / (float)B_ROWS));
}

// ---------------------------------------------------------------------------
extern "C" void kernel_launch(void* const* d_in, const int* in_sizes, int n_in,
                              void* d_out, int out_size, void* d_ws, size_t ws_size,
                              hipStream_t stream) {
    const float* feature = (const float*)d_in[0];  // 4096 x 2048
    const float* centers = (const float*)d_in[1];  // 2048 x 2048
    float* out = (float*)d_out;                    // scalar

    // Workspace layout (distances bf16, quantized inputs fp8)
    bf16_t* Dfc  = (bf16_t*)d_ws;                            // 4096*2048 bf16
    bf16_t* Dcc  = Dfc + (size_t)B_ROWS * C_ROWS;            // 2048*2048 bf16
    u8*     Fq   = (u8*)(Dcc + (size_t)C_ROWS * C_ROWS);     // 4096*2048 fp8
    u8*     Cq   = Fq + (size_t)B_ROWS * D_DIM;              // 2048*2048 fp8
    float*  f2   = (float*)(Cq + (size_t)C_ROWS * D_DIM);    // 4096
    float*  c2   = f2 + B_ROWS;                              // 2048

    // Cheap one-time capability probe (host-side API, capture-safe).
    static int coop_ok = -1;
    if (coop_ok < 0) {
        int dev = 0, v = 0;
        (void)hipGetDevice(&dev);
        if (hipDeviceGetAttribute(&v, hipDeviceAttributeCooperativeLaunch, dev) != hipSuccess) v = 0;
        coop_ok = v;
    }

    hipError_t err = hipErrorNotSupported;
    if (coop_ok) {
        void* args[] = {(void*)&feature, (void*)&centers, (void*)&Fq, (void*)&Cq,
                        (void*)&f2, (void*)&c2, (void*)&Dfc, (void*)&Dcc, (void*)&out};
        err = hipLaunchCooperativeKernel((const void*)(void*)fused_all,
                                         dim3(768), dim3(256), args, 0u, stream);
    }
    if (err != hipSuccess) {
        (void)hipGetLastError();  // clear sticky error; fall back to 3-kernel path
        conv_rows<<<(B_ROWS + C_ROWS) / 4, 256, 0, stream>>>(feature, centers, Fq, Cq,
                                                             f2, c2, out);
        gemm_d2_fused<<<dim3(C_ROWS / 128, B_ROWS / 128 + C_ROWS / 128), 256, 0, stream>>>(
            Fq, Cq, f2, c2, Dfc, Dcc);
        select_kernel<<<B_ROWS / 4, 256, 0, stream>>>(Dfc, Dcc, out, C_ROWS);
    }
}

// Round 2
// 142.644 us; speedup vs baseline: 2.3259x; 2.3259x over previous
//
#include <hip/hip_runtime.h>
#include <hip/hip_bf16.h>
#include <math.h>

// Problem constants (from reference)
#define B_ROWS 4096
#define C_ROWS 2048
#define D_DIM  2048
#define NUM 2
#define MAX_ITER 15
#define NEAREST 3
#define MARGIN 1.0f

typedef __bf16 bf16_t;
typedef bf16_t bf16x8 __attribute__((ext_vector_type(8)));
typedef float f32x4 __attribute__((ext_vector_type(4)));
typedef int i32x4 __attribute__((ext_vector_type(4)));
typedef int i32x8 __attribute__((ext_vector_type(8)));   // 32 fp8 bytes = scaled-MFMA fragment
typedef unsigned char u8;

// ---------------------------------------------------------------------------
// conv: one wave per row, f32 -> fp8 e4m3 (HW cvt_pk, OCP-native on gfx950)
// + row sumsq (exact, from f32) via shuffle. Verified R13/R14: absmax 0.0.
// Rows [0,4096) = feature, [4096,6144) = centers. 4 waves/block.
// Block 0 zero-inits out (select accumulates onto it; stream order).
// ---------------------------------------------------------------------------
__global__ __launch_bounds__(256) void conv_rows(const float* __restrict__ F,
                                                 const float* __restrict__ Cn,
                                                 u8* __restrict__ Fq,
                                                 u8* __restrict__ Cq,
                                                 float* __restrict__ f2,
                                                 float* __restrict__ c2,
                                                 float* __restrict__ out) {
    if (blockIdx.x == 0 && threadIdx.x == 0) out[0] = 0.0f;
    int wave = threadIdx.x >> 6;
    int lane = threadIdx.x & 63;
    int row = blockIdx.x * 4 + wave;          // 0..6143
    const float* p; u8* q; float* sq; int r;
    if (row < B_ROWS) {
        r = row; p = F + (size_t)r * D_DIM; q = Fq + (size_t)r * D_DIM; sq = f2;
    } else {
        r = row - B_ROWS; p = Cn + (size_t)r * D_DIM; q = Cq + (size_t)r * D_DIM; sq = c2;
    }
    float s = 0.0f;
    #pragma unroll
    for (int it = 0; it < 4; ++it) {
        int k = (it * 64 + lane) * 8;         // 8 consecutive floats per lane
        float4 v0 = *(const float4*)(p + k);
        float4 v1 = *(const float4*)(p + k + 4);
        s += v0.x * v0.x + v0.y * v0.y + v0.z * v0.z + v0.w * v0.w;
        s += v1.x * v1.x + v1.y * v1.y + v1.z * v1.z + v1.w * v1.w;
        int lo = __builtin_amdgcn_cvt_pk_fp8_f32(v0.x, v0.y, 0, 0);
        lo     = __builtin_amdgcn_cvt_pk_fp8_f32(v0.z, v0.w, lo, 1);
        int hi = __builtin_amdgcn_cvt_pk_fp8_f32(v1.x, v1.y, 0, 0);
        hi     = __builtin_amdgcn_cvt_pk_fp8_f32(v1.z, v1.w, hi, 1);
        int2 st; st.x = lo; st.y = hi;
        *(int2*)(q + k) = st;                 // 8 bytes, coalesced
    }
    #pragma unroll
    for (int off = 32; off >= 1; off >>= 1) s += __shfl_down(s, off);
    if (lane == 0) sq[r] = s;
}

// ---------------------------------------------------------------------------
// gemm_d2_8ph: fp8 MX-scaled (K=128) distance GEMM, 256x256 tile, BK=128,
// 8 waves (2M x 4N, per-wave 128x64 out), double-buffered LDS (128 KiB),
// phase-split schedule with COUNTED vmcnt (T3+T4) + setprio (T5).
//
// LDS layout: [256 rows][128 B] per buffer; 16B chunk c of row r at slot
// c ^ (r&7) (8 slots/row) -> every wave64 ds_read_b128 spreads uniformly
// 8 lanes / 4-bank-group = the b128 floor (T2-equivalent). Staged via
// global_load_lds (linear dest = wave-uniform base + lane*16) with the
// inverse swizzle applied to the per-lane GLOBAL source (m173 pattern):
// lane l of an issue covers row g*64 + (tid>>3), slot tid&7, content chunk
// (tid&7)^((tid>>3)&7)  [row&7 == tid>>3 &7, so slot^row&7 == chunk].
//
// Pipeline per K-tile t (reading buf p, staging t+1 into buf p^1):
//   ph0: issue B(t+1) [4 loads/thr]; ds_read 4 B-frags + A-frags 0,1;
//        barrier; setprio1; 8 MFMA; setprio0; barrier
//   ph1: issue A-sub0(t+1) rows{0-63,128-191} [2]; ds_read A 2,3;
//        barrier; MFMA x8; vmcnt(6); barrier      <- lands A-sub1(t)
//   ph2: ds_read A 4,5 (rows wm+64.. = A-sub1(t)); barrier; MFMA x8; barrier
//   ph3: issue A-sub1(t+1) rows{64-127,192-255} [2]; ds_read A 6,7;
//        barrier; MFMA x8; vmcnt(2); barrier      <- lands B+A-sub0(t+1),
//                                                    keeps A-sub1(t+1) IN FLIGHT
// Never drains vmcnt to 0 in the main loop (m218: drain-0 == no pipeline).
// Consumption check: ph0-1 read A rows [wm,wm+64) = A-sub0; ph2-3 read
// [wm+64,wm+128) = A-sub1; B fully read at ph0. Staging is symmetric across
// waves, so per-wave vmcnt + s_barrier is a collective landing guarantee.
//
// Fragment algebra (chunk/slot XOR, kg -> k-bytes kg*32, MFMA operands,
// C/D layout col=lane&15 row=(lane>>4)*4+reg) identical to the verified
// R14 kernel. MEASURED PITFALLS (do not revisit): R5 128B-row banking
// without swizzle; R7 nonzero imm offset on global_load_lds; R11 per-lane
// ROW scatter breaks coalescing; R13 unswizzled rows.
//   Out[m][n] = bf16( a2[m] + c2[n] - 2 * sum_k A[m][k]*Cb[n][k] )
// ---------------------------------------------------------------------------
__global__ __launch_bounds__(512, 2) void gemm_d2_8ph(const u8* __restrict__ Fq,
                                                      const u8* __restrict__ Cq,
                                                      const float* __restrict__ f2,
                                                      const float* __restrict__ c2,
                                                      bf16_t* __restrict__ Dfc,
                                                      bf16_t* __restrict__ Dcc) {
    __shared__ __align__(16) u8 As[2][256 * 128];   // 64 KiB
    __shared__ __align__(16) u8 Bs[2][256 * 128];   // 64 KiB

    const int tid  = threadIdx.x;
    const int wave = tid >> 6;
    const int lane = tid & 63;

    const int by = blockIdx.y;
    const u8* A; const float* a2v; bf16_t* Out; int bm;
    if (by < B_ROWS / 256) { A = Fq; a2v = f2; Out = Dfc; bm = by * 256; }
    else { A = Cq; a2v = c2; Out = Dcc; bm = (by - B_ROWS / 256) * 256; }
    const int bn = blockIdx.x * 256;
    const int N = C_ROWS, K = D_DIM;

    const int wm = (wave >> 2) * 128;     // 2M x 4N wave grid
    const int wn = (wave & 3) * 64;

    // staging constants (per thread)
    const int srow   = tid >> 3;                              // 0..63
    const int schunk = ((tid & 7) ^ ((tid >> 3) & 7)) * 16;   // inverse swizzle
    const int wbase  = wave * 1024;                           // wave-uniform LDS base part
    // read constants (per lane): slots of chunks 2kg, 2kg+1 for row with row&7==lane&7
    const int mrow = lane & 15;
    const int sl0  = (((lane >> 4) * 2    ) ^ (lane & 7)) * 16;
    const int sl1  = (((lane >> 4) * 2 + 1) ^ (lane & 7)) * 16;

    const u8* gA = A  + (size_t)(bm + srow) * K + schunk;     // + g*64*K + k0
    const u8* gB = Cq + (size_t)(bn + srow) * K + schunk;

    f32x4 acc[8][4] = {};

#define GLD(dst, src)                                                          \
    __builtin_amdgcn_global_load_lds(                                          \
        (const __attribute__((address_space(1))) void*)(src),                  \
        (__attribute__((address_space(3))) void*)(dst), 16, 0, 0)

    // stage helpers: B tile = groups 0..3; A-sub0 = groups {0,2}; A-sub1 = {1,3}
#define STAGE_B(nxtB, kk)                                                      \
    do { _Pragma("unroll") for (int g = 0; g < 4; ++g)                         \
        GLD((nxtB) + g * 8192 + wbase, gB + (size_t)g * 64 * K + (kk)); } while (0)
#define STAGE_A0(nxtA, kk)                                                     \
    do { GLD((nxtA) + 0 * 8192 + wbase, gA + (size_t)0 * 64 * K + (kk));       \
         GLD((nxtA) + 2 * 8192 + wbase, gA + (size_t)2 * 64 * K + (kk)); } while (0)
#define STAGE_A1(nxtA, kk)                                                     \
    do { GLD((nxtA) + 1 * 8192 + wbase, gA + (size_t)1 * 64 * K + (kk));       \
         GLD((nxtA) + 3 * 8192 + wbase, gA + (size_t)3 * 64 * K + (kk)); } while (0)

    auto rdfrag = [&](const u8* buf, int wrow, int i) -> i32x8 {
        const u8* p = buf + (wrow + i * 16 + mrow) * 128;
        i32x4 lo = *(const i32x4*)(p + sl0);
        i32x4 hi = *(const i32x4*)(p + sl1);
        i32x8 r;
        r[0] = lo.x; r[1] = lo.y; r[2] = lo.z; r[3] = lo.w;
        r[4] = hi.x; r[5] = hi.y; r[6] = hi.z; r[7] = hi.w;
        return r;
    };

#define MFMA8(A0, A1, I0)                                                      \
    do {                                                                       \
        __builtin_amdgcn_s_setprio(1);                                         \
        _Pragma("unroll") for (int j = 0; j < 4; ++j) {                        \
            acc[I0][j] = __builtin_amdgcn_mfma_scale_f32_16x16x128_f8f6f4(     \
                (A0), bfr[j], acc[I0][j], 0, 0, 0, 0x7F7F7F7F, 0, 0x7F7F7F7F); \
            acc[I0 + 1][j] = __builtin_amdgcn_mfma_scale_f32_16x16x128_f8f6f4( \
                (A1), bfr[j], acc[I0 + 1][j], 0, 0, 0, 0x7F7F7F7F, 0, 0x7F7F7F7F); \
        }                                                                      \
        __builtin_amdgcn_s_setprio(0);                                         \
    } while (0)

#define BAR() __builtin_amdgcn_s_barrier()
#define WAITV(n) asm volatile("s_waitcnt vmcnt(" #n ")" ::: "memory")

    // ---- prologue: stage full tile 0 into buf 0, drain, barrier ----
    STAGE_B(Bs[0], 0);
    STAGE_A0(As[0], 0);
    STAGE_A1(As[0], 0);
    WAITV(0);
    BAR();

    const u8* curA = As[0]; const u8* curB = Bs[0];
    u8* nxtA = As[1]; u8* nxtB = Bs[1];

    #pragma unroll 1
    for (int t = 0; t < 15; ++t) {
        const int kn = (t + 1) * 128;
        i32x8 bfr[4];
        // ---- ph0 ----
        STAGE_B(nxtB, kn);
        #pragma unroll
        for (int j = 0; j < 4; ++j) bfr[j] = rdfrag(curB, wn, j);
        {
            i32x8 a0 = rdfrag(curA, wm, 0), a1 = rdfrag(curA, wm, 1);
            BAR();
            MFMA8(a0, a1, 0);
            BAR();
        }
        // ---- ph1 ----
        STAGE_A0(nxtA, kn);
        {
            i32x8 a0 = rdfrag(curA, wm, 2), a1 = rdfrag(curA, wm, 3);
            BAR();
            MFMA8(a0, a1, 2);
            WAITV(6);            // lands A-sub1(t); keeps B,A-sub0(t+1) in flight
            BAR();
        }
        // ---- ph2 ----
        {
            i32x8 a0 = rdfrag(curA, wm, 4), a1 = rdfrag(curA, wm, 5);
            BAR();
            MFMA8(a0, a1, 4);
            BAR();
        }
        // ---- ph3 ----
        STAGE_A1(nxtA, kn);
        {
            i32x8 a0 = rdfrag(curA, wm, 6), a1 = rdfrag(curA, wm, 7);
            BAR();
            MFMA8(a0, a1, 6);
            WAITV(2);            // lands B,A-sub0(t+1); A-sub1(t+1) stays in flight
            BAR();
        }
        // swap buffers
        { const u8* tA = curA; curA = (const u8*)nxtA; nxtA = (u8*)tA; }
        { const u8* tB = curB; curB = (const u8*)nxtB; nxtB = (u8*)tB; }
    }

    // ---- peeled last tile (t=15): no staging ----
    {
        i32x8 bfr[4];
        #pragma unroll
        for (int j = 0; j < 4; ++j) bfr[j] = rdfrag(curB, wn, j);
        {
            i32x8 a0 = rdfrag(curA, wm, 0), a1 = rdfrag(curA, wm, 1);
            BAR();
            MFMA8(a0, a1, 0);
            BAR();
        }
        {
            i32x8 a0 = rdfrag(curA, wm, 2), a1 = rdfrag(curA, wm, 3);
            BAR();
            MFMA8(a0, a1, 2);
            WAITV(0);            // land A-sub1(15) before ph2 reads it
            BAR();
        }
        {
            i32x8 a0 = rdfrag(curA, wm, 4), a1 = rdfrag(curA, wm, 5);
            BAR();
            MFMA8(a0, a1, 4);
            BAR();
        }
        {
            i32x8 a0 = rdfrag(curA, wm, 6), a1 = rdfrag(curA, wm, 7);
            BAR();
            MFMA8(a0, a1, 6);
        }
    }

    // ---- epilogue: d2 = a2[m] + c2[n] - 2*dot, stored bf16 ----
    // C/D layout shape-determined, dtype-independent: col=lane&15, row=(lane>>4)*4+reg
    const int ncol = lane & 15;
    const int r4   = (lane >> 4) * 4;
    #pragma unroll
    for (int i = 0; i < 8; ++i) {
        #pragma unroll
        for (int r = 0; r < 4; ++r) {
            int m = bm + wm + i * 16 + r4 + r;
            float am = a2v[m];
            #pragma unroll
            for (int j = 0; j < 4; ++j) {
                int n = bn + wn + j * 16 + ncol;
                Out[(size_t)m * N + n] = (bf16_t)(am + c2[n] - 2.0f * acc[i][j][r]);
            }
        }
    }
#undef GLD
#undef STAGE_B
#undef STAGE_A0
#undef STAGE_A1
#undef MFMA8
#undef BAR
#undef WAITV
}

// ---------------------------------------------------------------------------
// select v3: bf16 distance rows, vectorized 16B loads.
// Iterative argmin w/ exclusion over Dfc row; on-demand trust from Dcc:
//   label in near3[sel]  <=>  #{ j : (Dcc[sel][j], j) <lex (Dcc[sel][label],
//   label) } < NEAREST   (stable argsort -> lexicographic order)
// Ownership: lane l, group g, sub e: n = g*512 + l*8 + e; excl bit g*8+e.
// 4 waves/block, one row per wave; one atomicAdd per block onto out.
// ---------------------------------------------------------------------------
__global__ __launch_bounds__(256) void select_kernel(const bf16_t* __restrict__ Dfc,
                                                     const bf16_t* __restrict__ Dcc,
                                                     float* __restrict__ out, int C) {
    int wave = threadIdx.x >> 6, lane = threadIdx.x & 63;
    int b = blockIdx.x * 4 + wave;
    int label = b / NUM;
    const bf16_t* row = Dfc + (size_t)b * C;

    float vals[32];
    #pragma unroll
    for (int g = 0; g < 4; ++g) {
        bf16x8 v = *(const bf16x8*)(row + g * 512 + lane * 8);
        #pragma unroll
        for (int e = 0; e < 8; ++e) {
            int n = g * 512 + lane * 8 + e;
            float f = (float)v[e];
            vals[g * 8 + e] = (n == label) ? INFINITY : f;
        }
    }

    unsigned int excl = 0;
    float min_diff = 0.0f;
    int found = 0;
    for (int it = 0; it < MAX_ITER; ++it) {
        float bestv = INFINITY; int bestidx = 0x7fffffff;
        #pragma unroll
        for (int g = 0; g < 4; ++g)
            #pragma unroll
            for (int e = 0; e < 8; ++e) {
                int bit = g * 8 + e;
                if (excl & (1u << bit)) continue;
                float v = vals[bit];
                int idx = g * 512 + lane * 8 + e;
                if (v < bestv || (v == bestv && idx < bestidx)) { bestv = v; bestidx = idx; }
            }
        for (int off = 32; off >= 1; off >>= 1) {
            float ov = __shfl_down(bestv, off); int oi = __shfl_down(bestidx, off);
            if (ov < bestv || (ov == bestv && oi < bestidx)) { bestv = ov; bestidx = oi; }
        }
        int sel = __shfl(bestidx, 0);
        float selv = __shfl(bestv, 0);

        // --- on-demand trust: count lex-smaller entries of Dcc row sel ---
        const bf16_t* crow = Dcc + (size_t)sel * C;
        float dl = (float)crow[label];          // uniform address: broadcast
        int cnt = 0;
        #pragma unroll
        for (int g = 0; g < 4; ++g) {
            bf16x8 v = *(const bf16x8*)(crow + g * 512 + lane * 8);
            #pragma unroll
            for (int e = 0; e < 8; ++e) {
                int idx = g * 512 + lane * 8 + e;
                float f = (float)v[e];
                cnt += (f < dl || (f == dl && idx < label)) ? 1 : 0;
            }
        }
        #pragma unroll
        for (int off = 32; off >= 1; off >>= 1) cnt += __shfl_down(cnt, off);
        cnt = __shfl(cnt, 0);
        bool trusted = (cnt >= NEAREST);

        if (trusted) { min_diff = sqrtf(fmaxf(selv, 0.0f)); found = 1; break; }
        if (((sel >> 3) & 63) == lane) excl |= 1u << (((sel >> 9) << 3) | (sel & 7));
    }
    __shared__ float hs[4];
    if (lane == 0) {
        float same = sqrtf(fmaxf((float)row[label], 0.0f));
        float md = found ? min_diff : 0.0f;
        hs[wave] = fmaxf(MARGIN + same - md, 0.0f);
    }
    __syncthreads();
    if (threadIdx.x == 0)
        atomicAdd(out, (hs[0] + hs[1] + hs[2] + hs[3]) * (1.0f / (float)B_ROWS));
}

// ---------------------------------------------------------------------------
extern "C" void kernel_launch(void* const* d_in, const int* in_sizes, int n_in,
                              void* d_out, int out_size, void* d_ws, size_t ws_size,
                              hipStream_t stream) {
    const float* feature = (const float*)d_in[0];  // 4096 x 2048
    const float* centers = (const float*)d_in[1];  // 2048 x 2048
    float* out = (float*)d_out;                    // scalar

    // Workspace layout (distances bf16, quantized inputs fp8)
    bf16_t* Dfc  = (bf16_t*)d_ws;                            // 4096*2048 bf16
    bf16_t* Dcc  = Dfc + (size_t)B_ROWS * C_ROWS;            // 2048*2048 bf16
    u8*     Fq   = (u8*)(Dcc + (size_t)C_ROWS * C_ROWS);     // 4096*2048 fp8
    u8*     Cq   = Fq + (size_t)B_ROWS * D_DIM;              // 2048*2048 fp8
    float*  f2   = (float*)(Cq + (size_t)C_ROWS * D_DIM);    // 4096
    float*  c2   = f2 + B_ROWS;                              // 2048

    conv_rows<<<(B_ROWS + C_ROWS) / 4, 256, 0, stream>>>(feature, centers, Fq, Cq,
                                                         f2, c2, out);

    // Both distance matrices in one dispatch: grid (8, 16+8) = 192 blocks,
    // 512 threads (8 waves), 128 KiB LDS -> 1 block/CU.
    gemm_d2_8ph<<<dim3(C_ROWS / 256, B_ROWS / 256 + C_ROWS / 256), 512, 0, stream>>>(
        Fq, Cq, f2, c2, Dfc, Dcc);

    // select with on-demand trust (reads Dcc directly; no near3 dispatch).
    select_kernel<<<B_ROWS / 4, 256, 0, stream>>>(Dfc, Dcc, out, C_ROWS);
}

// Round 3
// 136.177 us; speedup vs baseline: 2.4364x; 1.0475x over previous
//
#include <hip/hip_runtime.h>
#include <hip/hip_bf16.h>
#include <math.h>

// Problem constants (from reference)
#define B_ROWS 4096
#define C_ROWS 2048
#define D_DIM  2048
#define NUM 2
#define MAX_ITER 15
#define NEAREST 3
#define MARGIN 1.0f

typedef __bf16 bf16_t;
typedef bf16_t bf16x8 __attribute__((ext_vector_type(8)));
typedef float f32x4 __attribute__((ext_vector_type(4)));
typedef float f32x16 __attribute__((ext_vector_type(16)));
typedef int i32x4 __attribute__((ext_vector_type(4)));
typedef int i32x8 __attribute__((ext_vector_type(8)));   // 32 fp8 bytes = scaled-MFMA fragment
typedef unsigned char u8;

// ---------------------------------------------------------------------------
// conv: one wave per row, f32 -> fp8 e4m3 (HW cvt_pk, OCP-native on gfx950)
// + row sumsq (exact, from f32) via shuffle. Verified R13/R14: absmax 0.0.
// Rows [0,4096) = feature, [4096,6144) = centers. 4 waves/block.
// Block 0 zero-inits out (select accumulates onto it; stream order).
// ---------------------------------------------------------------------------
__global__ __launch_bounds__(256) void conv_rows(const float* __restrict__ F,
                                                 const float* __restrict__ Cn,
                                                 u8* __restrict__ Fq,
                                                 u8* __restrict__ Cq,
                                                 float* __restrict__ f2,
                                                 float* __restrict__ c2,
                                                 float* __restrict__ out) {
    if (blockIdx.x == 0 && threadIdx.x == 0) out[0] = 0.0f;
    int wave = threadIdx.x >> 6;
    int lane = threadIdx.x & 63;
    int row = blockIdx.x * 4 + wave;          // 0..6143
    const float* p; u8* q; float* sq; int r;
    if (row < B_ROWS) {
        r = row; p = F + (size_t)r * D_DIM; q = Fq + (size_t)r * D_DIM; sq = f2;
    } else {
        r = row - B_ROWS; p = Cn + (size_t)r * D_DIM; q = Cq + (size_t)r * D_DIM; sq = c2;
    }
    float s = 0.0f;
    #pragma unroll
    for (int it = 0; it < 4; ++it) {
        int k = (it * 64 + lane) * 8;         // 8 consecutive floats per lane
        float4 v0 = *(const float4*)(p + k);
        float4 v1 = *(const float4*)(p + k + 4);
        s += v0.x * v0.x + v0.y * v0.y + v0.z * v0.z + v0.w * v0.w;
        s += v1.x * v1.x + v1.y * v1.y + v1.z * v1.z + v1.w * v1.w;
        int lo = __builtin_amdgcn_cvt_pk_fp8_f32(v0.x, v0.y, 0, 0);
        lo     = __builtin_amdgcn_cvt_pk_fp8_f32(v0.z, v0.w, lo, 1);
        int hi = __builtin_amdgcn_cvt_pk_fp8_f32(v1.x, v1.y, 0, 0);
        hi     = __builtin_amdgcn_cvt_pk_fp8_f32(v1.z, v1.w, hi, 1);
        int2 st; st.x = lo; st.y = hi;
        *(int2*)(q + k) = st;                 // 8 bytes, coalesced
    }
    #pragma unroll
    for (int off = 32; off >= 1; off >>= 1) s += __shfl_down(s, off);
    if (lane == 0) sq[r] = s;
}

// ---------------------------------------------------------------------------
// gemm_d2_p3: fp8 MX-scaled distance GEMM, 128x128 tile, 768 blocks
// (3 blocks/CU resident, 12 waves/CU -> m114 inter-block overlap), 4 waves
// of 64x64 (2x2 of 32x32 frags), MFMA 32x32x64 f8f6f4 (K=64/instr).
// TRIPLE-buffered BK=64 panels (3 x (8KB A + 8KB B) = 48 KB LDS, keeps
// 3 blocks/CU) with COUNTED vmcnt(4): STAGE(p+2) issued at top of panel p,
// wait vmcnt(4) at end (lands STAGE(p+1), keeps STAGE(p+2) in flight) —
// never drains in the main loop (T4, m218). One barrier per panel.
//
// LDS layout: [128 rows][64 B] per panel; 16B chunk c of row r at slot
// c ^ ((r>>1)&3)  (R14's verified swizzle). Staged via global_load_lds
// (dest = wave-uniform base + lane*16) with the inverse swizzle on the
// per-lane GLOBAL source: thread t covers row g*64 + (t>>2), slot t&3,
// source chunk (lane&3)^((lane>>3)&3) — identical kbyt to R14 (verified
// coalescing: each 4 lanes = one 64B segment).
// Read: lane l holds A row l&31, k-bytes (l>>5)*32 (extends the VERIFIED
// 16x16x128 mapping row=l&15, kg=l>>4); two ds_read_b128 at slots
// (2h)^swr, (2h+1)^swr, swr=((l&31)>>1)&3. Enumerated: 8 lanes per 16B
// bank-group = conflict floor.
// C/D 32x32 layout (m74/m101, dtype-indep): col=lane&31,
// row=(reg&3)+8*(reg>>2)+4*(lane>>5).
// MEASURED PITFALLS (do not revisit): R5 128B-row banking w/o swizzle;
// R7 nonzero imm offset on global_load_lds; R11 per-lane ROW scatter;
// R13 unswizzled rows; R2-8ph 1-block/CU lockstep (45us, MfmaUtil 20%).
//   Out[m][n] = bf16( a2[m] + c2[n] - 2 * sum_k A[m][k]*Cb[n][k] )
// ---------------------------------------------------------------------------
__global__ __launch_bounds__(256, 3) void gemm_d2_p3(const u8* __restrict__ Fq,
                                                     const u8* __restrict__ Cq,
                                                     const float* __restrict__ f2,
                                                     const float* __restrict__ c2,
                                                     bf16_t* __restrict__ Dfc,
                                                     bf16_t* __restrict__ Dcc) {
    __shared__ __align__(16) u8 As[3][128 * 64];   // 24 KiB
    __shared__ __align__(16) u8 Bs[3][128 * 64];   // 24 KiB

    const int tid  = threadIdx.x;
    const int wave = tid >> 6;
    const int lane = tid & 63;

    const int by = blockIdx.y;
    const u8* A; const float* a2v; bf16_t* Out; int bm;
    if (by < B_ROWS / 128) { A = Fq; a2v = f2; Out = Dfc; bm = by * 128; }
    else { A = Cq; a2v = c2; Out = Dcc; bm = (by - B_ROWS / 128) * 128; }
    const int bn = blockIdx.x * 128;
    const int N = C_ROWS, K = D_DIM;

    const int wmL = (wave >> 1) * 64;     // 2x2 wave grid, 64x64 per wave
    const int wnL = (wave & 1) * 64;

    // staging constants: thread t -> row g*64 + wave*16 + (lane>>2), slot lane&3,
    // source chunk (lane&3)^((lane>>3)&3)  [== slot ^ ((row>>1)&3)]
    const int kbyt  = ((lane & 3) ^ ((lane >> 3) & 3)) * 16;
    const int wbase = wave * 1024;                      // wave-uniform LDS base part
    const u8* gA = A  + (size_t)(bm + wave * 16 + (lane >> 2)) * K + kbyt;
    const u8* gB = Cq + (size_t)(bn + wave * 16 + (lane >> 2)) * K + kbyt;

    // read constants: m31 = row-in-frag, h = k-half, swr = row swizzle
    const int m31 = lane & 31;
    const int h   = lane >> 5;
    const int swr = (m31 >> 1) & 3;
    const int sl0 = ((h * 2    ) ^ swr) * 16;
    const int sl1 = ((h * 2 + 1) ^ swr) * 16;

    f32x16 acc[2][2] = {};

#define GLD(dst, src)                                                          \
    __builtin_amdgcn_global_load_lds(                                          \
        (const __attribute__((address_space(1))) void*)(src),                  \
        (__attribute__((address_space(3))) void*)(dst), 16, 0, 0)

    // stage panel p (k-offset p*64) into buffer q: 4 GLD/thread (2 A + 2 B)
#define STAGE(q, p)                                                            \
    do {                                                                       \
        GLD(&As[q][0 * 4096 + wbase], gA + (size_t)0 * 64 * K + (p) * 64);     \
        GLD(&As[q][1 * 4096 + wbase], gA + (size_t)1 * 64 * K + (p) * 64);     \
        GLD(&Bs[q][0 * 4096 + wbase], gB + (size_t)0 * 64 * K + (p) * 64);     \
        GLD(&Bs[q][1 * 4096 + wbase], gB + (size_t)1 * 64 * K + (p) * 64);     \
    } while (0)

    auto rd = [&](const u8* buf, int rowbase) -> i32x8 {
        const u8* pp = buf + rowbase * 64;
        i32x4 lo = *(const i32x4*)(pp + sl0);
        i32x4 hi = *(const i32x4*)(pp + sl1);
        i32x8 r;
        r[0] = lo.x; r[1] = lo.y; r[2] = lo.z; r[3] = lo.w;
        r[4] = hi.x; r[5] = hi.y; r[6] = hi.z; r[7] = hi.w;
        return r;
    };

    // one panel's compute: 4 frag reads (8 ds_read_b128), 4 MFMA 32x32x64
#define PANEL(q)                                                               \
    do {                                                                       \
        i32x8 a0 = rd(As[q], wmL + m31);                                       \
        i32x8 a1 = rd(As[q], wmL + 32 + m31);                                  \
        i32x8 b0 = rd(Bs[q], wnL + m31);                                       \
        i32x8 b1 = rd(Bs[q], wnL + 32 + m31);                                  \
        __builtin_amdgcn_s_setprio(1);                                         \
        acc[0][0] = __builtin_amdgcn_mfma_scale_f32_32x32x64_f8f6f4(           \
            a0, b0, acc[0][0], 0, 0, 0, 0x7F7F7F7F, 0, 0x7F7F7F7F);            \
        acc[0][1] = __builtin_amdgcn_mfma_scale_f32_32x32x64_f8f6f4(           \
            a0, b1, acc[0][1], 0, 0, 0, 0x7F7F7F7F, 0, 0x7F7F7F7F);            \
        acc[1][0] = __builtin_amdgcn_mfma_scale_f32_32x32x64_f8f6f4(           \
            a1, b0, acc[1][0], 0, 0, 0, 0x7F7F7F7F, 0, 0x7F7F7F7F);            \
        acc[1][1] = __builtin_amdgcn_mfma_scale_f32_32x32x64_f8f6f4(           \
            a1, b1, acc[1][1], 0, 0, 0, 0x7F7F7F7F, 0, 0x7F7F7F7F);            \
        __builtin_amdgcn_s_setprio(0);                                         \
    } while (0)

#define BAR() __builtin_amdgcn_s_barrier()
#define WAITV(n) asm volatile("s_waitcnt vmcnt(" #n ")" ::: "memory")

    // prologue: panels 0,1 in flight; land 0; collective barrier
    STAGE(0, 0);
    STAGE(1, 1);
    WAITV(4);
    BAR();

    // main loop: 30 panels, 3-unrolled so buffer index is compile-time.
    // iter(p): STAGE(p+2) -> compute(p) -> vmcnt(4) [lands p+1] -> barrier
    #pragma unroll 1
    for (int pb = 0; pb < 30; pb += 3) {
        STAGE(2, pb + 2);
        PANEL(0);
        WAITV(4);
        BAR();
        STAGE(0, pb + 3);
        PANEL(1);
        WAITV(4);
        BAR();
        STAGE(1, pb + 4);
        PANEL(2);
        WAITV(4);
        BAR();
    }
    // Loop staged panels up to 31 inclusive (pb=27: stages 29,30,31) and
    // computed 0..29; after the last vmcnt(4), panel 30 landed, 31 in flight.
    PANEL(0);            // panel 30 (30 % 3 == 0)
    WAITV(0);            // drain panel 31
    BAR();
    PANEL(1);            // panel 31

    // ---- epilogue: d2 = a2[m] + c2[n] - 2*dot, stored bf16 ----
    // 32x32 C/D: col = lane&31, row = (reg&3) + 8*(reg>>2) + 4*(lane>>5)
    #pragma unroll
    for (int i = 0; i < 2; ++i) {
        #pragma unroll
        for (int r = 0; r < 16; ++r) {
            int m = bm + wmL + i * 32 + (r & 3) + 8 * (r >> 2) + 4 * h;
            float am = a2v[m];
            #pragma unroll
            for (int j = 0; j < 2; ++j) {
                int n = bn + wnL + j * 32 + m31;
                Out[(size_t)m * N + n] = (bf16_t)(am + c2[n] - 2.0f * acc[i][j][r]);
            }
        }
    }
#undef GLD
#undef STAGE
#undef PANEL
#undef BAR
#undef WAITV
}

// ---------------------------------------------------------------------------
// select v3: bf16 distance rows, vectorized 16B loads.
// Iterative argmin w/ exclusion over Dfc row; on-demand trust from Dcc:
//   label in near3[sel]  <=>  #{ j : (Dcc[sel][j], j) <lex (Dcc[sel][label],
//   label) } < NEAREST   (stable argsort -> lexicographic order)
// Ownership: lane l, group g, sub e: n = g*512 + l*8 + e; excl bit g*8+e.
// 4 waves/block, one row per wave; one atomicAdd per block onto out.
// ---------------------------------------------------------------------------
__global__ __launch_bounds__(256) void select_kernel(const bf16_t* __restrict__ Dfc,
                                                     const bf16_t* __restrict__ Dcc,
                                                     float* __restrict__ out, int C) {
    int wave = threadIdx.x >> 6, lane = threadIdx.x & 63;
    int b = blockIdx.x * 4 + wave;
    int label = b / NUM;
    const bf16_t* row = Dfc + (size_t)b * C;

    float vals[32];
    #pragma unroll
    for (int g = 0; g < 4; ++g) {
        bf16x8 v = *(const bf16x8*)(row + g * 512 + lane * 8);
        #pragma unroll
        for (int e = 0; e < 8; ++e) {
            int n = g * 512 + lane * 8 + e;
            float f = (float)v[e];
            vals[g * 8 + e] = (n == label) ? INFINITY : f;
        }
    }

    unsigned int excl = 0;
    float min_diff = 0.0f;
    int found = 0;
    for (int it = 0; it < MAX_ITER; ++it) {
        float bestv = INFINITY; int bestidx = 0x7fffffff;
        #pragma unroll
        for (int g = 0; g < 4; ++g)
            #pragma unroll
            for (int e = 0; e < 8; ++e) {
                int bit = g * 8 + e;
                if (excl & (1u << bit)) continue;
                float v = vals[bit];
                int idx = g * 512 + lane * 8 + e;
                if (v < bestv || (v == bestv && idx < bestidx)) { bestv = v; bestidx = idx; }
            }
        for (int off = 32; off >= 1; off >>= 1) {
            float ov = __shfl_down(bestv, off); int oi = __shfl_down(bestidx, off);
            if (ov < bestv || (ov == bestv && oi < bestidx)) { bestv = ov; bestidx = oi; }
        }
        int sel = __shfl(bestidx, 0);
        float selv = __shfl(bestv, 0);

        // --- on-demand trust: count lex-smaller entries of Dcc row sel ---
        const bf16_t* crow = Dcc + (size_t)sel * C;
        float dl = (float)crow[label];          // uniform address: broadcast
        int cnt = 0;
        #pragma unroll
        for (int g = 0; g < 4; ++g) {
            bf16x8 v = *(const bf16x8*)(crow + g * 512 + lane * 8);
            #pragma unroll
            for (int e = 0; e < 8; ++e) {
                int idx = g * 512 + lane * 8 + e;
                float f = (float)v[e];
                cnt += (f < dl || (f == dl && idx < label)) ? 1 : 0;
            }
        }
        #pragma unroll
        for (int off = 32; off >= 1; off >>= 1) cnt += __shfl_down(cnt, off);
        cnt = __shfl(cnt, 0);
        bool trusted = (cnt >= NEAREST);

        if (trusted) { min_diff = sqrtf(fmaxf(selv, 0.0f)); found = 1; break; }
        if (((sel >> 3) & 63) == lane) excl |= 1u << (((sel >> 9) << 3) | (sel & 7));
    }
    __shared__ float hs[4];
    if (lane == 0) {
        float same = sqrtf(fmaxf((float)row[label], 0.0f));
        float md = found ? min_diff : 0.0f;
        hs[wave] = fmaxf(MARGIN + same - md, 0.0f);
    }
    __syncthreads();
    if (threadIdx.x == 0)
        atomicAdd(out, (hs[0] + hs[1] + hs[2] + hs[3]) * (1.0f / (float)B_ROWS));
}

// ---------------------------------------------------------------------------
extern "C" void kernel_launch(void* const* d_in, const int* in_sizes, int n_in,
                              void* d_out, int out_size, void* d_ws, size_t ws_size,
                              hipStream_t stream) {
    const float* feature = (const float*)d_in[0];  // 4096 x 2048
    const float* centers = (const float*)d_in[1];  // 2048 x 2048
    float* out = (float*)d_out;                    // scalar

    // Workspace layout (distances bf16, quantized inputs fp8)
    bf16_t* Dfc  = (bf16_t*)d_ws;                            // 4096*2048 bf16
    bf16_t* Dcc  = Dfc + (size_t)B_ROWS * C_ROWS;            // 2048*2048 bf16
    u8*     Fq   = (u8*)(Dcc + (size_t)C_ROWS * C_ROWS);     // 4096*2048 fp8
    u8*     Cq   = Fq + (size_t)B_ROWS * D_DIM;              // 2048*2048 fp8
    float*  f2   = (float*)(Cq + (size_t)C_ROWS * D_DIM);    // 4096
    float*  c2   = f2 + B_ROWS;                              // 2048

    conv_rows<<<(B_ROWS + C_ROWS) / 4, 256, 0, stream>>>(feature, centers, Fq, Cq,
                                                         f2, c2, out);

    // Both distance matrices in one dispatch: grid (16, 32+16) = 768 blocks,
    // 256 threads (4 waves), 48 KiB LDS -> 3 blocks/CU resident.
    gemm_d2_p3<<<dim3(C_ROWS / 128, B_ROWS / 128 + C_ROWS / 128), 256, 0, stream>>>(
        Fq, Cq, f2, c2, Dfc, Dcc);

    // select with on-demand trust (reads Dcc directly; no near3 dispatch).
    select_kernel<<<B_ROWS / 4, 256, 0, stream>>>(Dfc, Dcc, out, C_ROWS);
}